// Round 1
// baseline (13961.929 us; speedup 1.0000x reference)
//
#include <hip/hip_runtime.h>
#include <math.h>

#define D_EMB 2048
#define NH 16
#define DK 128
#define SEQN 128
#define DFF 8192
#define VOCAB 30000
#define NLAYERS 6

// ---------------------------------------------------------------------------
// x7 + sinusoidal PE  -> X [128, 2048]
// pe[l, 2i]   = sin(l * 10000^(-2i/2048))
// pe[l, 2i+1] = cos(l * 10000^(-2i/2048))
// ---------------------------------------------------------------------------
__global__ __launch_bounds__(256) void add_pe_kernel(const float* __restrict__ x,
                                                     float* __restrict__ out) {
    int idx = blockIdx.x * 256 + threadIdx.x;      // 0 .. 128*2048-1
    int l = idx >> 11;
    int d = idx & 2047;
    float two_i = (float)(d & ~1);
    float div = __expf(-9.210340371976184f * two_i * (1.0f / 2048.0f)); // ln(1e4)
    float ang = (float)l * div;
    float pe = (d & 1) ? cosf(ang) : sinf(ang);
    out[idx] = x[(size_t)7 * SEQN * D_EMB + idx] + pe;
}

// ---------------------------------------------------------------------------
// C = A[M,K] @ B[N,K]^T (+bias)(+relu).  blockIdx.z selects among up to 3
// (B, bias, C) sets so independent projections (Q/K/V) fill the GPU in one
// launch. Tile 64x64, 256 threads, 4x4 accum per thread.
// M is always a multiple of 64 here; N may be ragged (30000).
// ---------------------------------------------------------------------------
#define BM 64
#define BN 64
#define BK 16

__global__ __launch_bounds__(256) void gemm_bt_kernel(
    const float* __restrict__ A,
    const float* __restrict__ B0, const float* __restrict__ B1, const float* __restrict__ B2,
    const float* __restrict__ bias0, const float* __restrict__ bias1, const float* __restrict__ bias2,
    float* __restrict__ C0, float* __restrict__ C1, float* __restrict__ C2,
    int M, int N, int K, int relu)
{
    const float* B    = (blockIdx.z == 0) ? B0    : (blockIdx.z == 1) ? B1    : B2;
    const float* bias = (blockIdx.z == 0) ? bias0 : (blockIdx.z == 1) ? bias1 : bias2;
    float*       C    = (blockIdx.z == 0) ? C0    : (blockIdx.z == 1) ? C1    : C2;

    __shared__ float As[BK][BM + 1];
    __shared__ float Bs[BK][BN + 1];

    int tid = threadIdx.x;
    int tx = tid & 15;        // 0..15 -> 4 cols each
    int ty = tid >> 4;        // 0..15 -> 4 rows each
    int m0 = blockIdx.x * BM;
    int n0 = blockIdx.y * BN;

    float acc[4][4] = {};

    for (int k0 = 0; k0 < K; k0 += BK) {
        #pragma unroll
        for (int r = 0; r < 4; ++r) {
            int idx = tid + r * 256;          // 0..1023
            int m = idx >> 4;
            int k = idx & 15;
            As[k][m] = A[(size_t)(m0 + m) * K + (k0 + k)];
        }
        #pragma unroll
        for (int r = 0; r < 4; ++r) {
            int idx = tid + r * 256;
            int n = idx >> 4;
            int k = idx & 15;
            int gn = n0 + n;
            Bs[k][n] = (gn < N) ? B[(size_t)gn * K + (k0 + k)] : 0.0f;
        }
        __syncthreads();
        #pragma unroll
        for (int k = 0; k < BK; ++k) {
            float a[4], b[4];
            #pragma unroll
            for (int i = 0; i < 4; ++i) a[i] = As[k][ty * 4 + i];
            #pragma unroll
            for (int j = 0; j < 4; ++j) b[j] = Bs[k][tx * 4 + j];
            #pragma unroll
            for (int i = 0; i < 4; ++i)
                #pragma unroll
                for (int j = 0; j < 4; ++j)
                    acc[i][j] += a[i] * b[j];
        }
        __syncthreads();
    }

    #pragma unroll
    for (int i = 0; i < 4; ++i) {
        int m = m0 + ty * 4 + i;
        #pragma unroll
        for (int j = 0; j < 4; ++j) {
            int n = n0 + tx * 4 + j;
            if (n < N) {
                float v = acc[i][j] + (bias ? bias[n] : 0.0f);
                if (relu) v = fmaxf(v, 0.0f);
                C[(size_t)m * N + n] = v;
            }
        }
    }
}

// ---------------------------------------------------------------------------
// Per-token "attention" (the faithful bug: batched matmul broadcasts over
// (B, L), so token l attends only to itself, over the d_k axis).
//   Q_l[i,h] = q[h*128+i];  S[i,j] = scale * sum_h q[h*128+i]*k[h*128+j]
//   causal: S[i,j] = -inf for j > i   (the [L,L] mask lands in the dk x dk plane)
//   A[i,h] = sum_j softmax_row_i(S)[j] * v[h*128+j];  out[h*128+i] = A[i,h]
// One block (128 threads) per token; thread i owns score-row i (online softmax).
// ---------------------------------------------------------------------------
__global__ __launch_bounds__(128) void attn_token_kernel(
    const float* __restrict__ Q, const float* __restrict__ K,
    const float* __restrict__ V, float* __restrict__ O, int causal)
{
    int l = blockIdx.x;
    int i = threadIdx.x;      // 0..127
    __shared__ float qs[D_EMB];
    __shared__ float ks[D_EMB];
    __shared__ float vs[D_EMB];
    for (int d = i; d < D_EMB; d += 128) {
        qs[d] = Q[(size_t)l * D_EMB + d];
        ks[d] = K[(size_t)l * D_EMB + d];
        vs[d] = V[(size_t)l * D_EMB + d];
    }
    __syncthreads();

    const float scale = 0.088388347648318447f;   // 1/sqrt(128)
    float qr[NH];
    #pragma unroll
    for (int h = 0; h < NH; ++h) qr[h] = qs[h * DK + i];

    int jmax = causal ? (i + 1) : DK;

    // pass 1: online max + sum
    float m = -INFINITY, lsum = 0.0f;
    for (int j = 0; j < jmax; ++j) {
        float s = 0.0f;
        #pragma unroll
        for (int h = 0; h < NH; ++h) s += qr[h] * ks[h * DK + j];
        s *= scale;
        float nm = fmaxf(m, s);
        lsum = lsum * __expf(m - nm) + __expf(s - nm);
        m = nm;
    }
    float rinv = 1.0f / lsum;

    // pass 2: weighted V accumulation
    float acc[NH];
    #pragma unroll
    for (int h = 0; h < NH; ++h) acc[h] = 0.0f;
    for (int j = 0; j < jmax; ++j) {
        float s = 0.0f;
        #pragma unroll
        for (int h = 0; h < NH; ++h) s += qr[h] * ks[h * DK + j];
        float p = __expf(s * scale - m) * rinv;
        #pragma unroll
        for (int h = 0; h < NH; ++h) acc[h] += p * vs[h * DK + j];
    }
    #pragma unroll
    for (int h = 0; h < NH; ++h)
        O[(size_t)l * D_EMB + h * DK + i] = acc[h];
}

// ---------------------------------------------------------------------------
// Row LayerNorm: y = g*(x-mean)*rsqrt(var+1e-5)+b  (biased var), row = 2048
// ---------------------------------------------------------------------------
__global__ __launch_bounds__(256) void layernorm_kernel(
    const float* __restrict__ X, const float* __restrict__ g,
    const float* __restrict__ b, float* __restrict__ Y)
{
    int row = blockIdx.x;
    const float* x = X + (size_t)row * D_EMB;
    float* y = Y + (size_t)row * D_EMB;
    __shared__ float buf[256];
    int tid = threadIdx.x;

    float s = 0.0f;
    for (int d = tid; d < D_EMB; d += 256) s += x[d];
    buf[tid] = s; __syncthreads();
    for (int off = 128; off; off >>= 1) {
        if (tid < off) buf[tid] += buf[tid + off];
        __syncthreads();
    }
    float mean = buf[0] * (1.0f / D_EMB);
    __syncthreads();

    float vsum = 0.0f;
    for (int d = tid; d < D_EMB; d += 256) {
        float t = x[d] - mean;
        vsum += t * t;
    }
    buf[tid] = vsum; __syncthreads();
    for (int off = 128; off; off >>= 1) {
        if (tid < off) buf[tid] += buf[tid + off];
        __syncthreads();
    }
    float inv = rsqrtf(buf[0] * (1.0f / D_EMB) + 1e-5f);

    for (int d = tid; d < D_EMB; d += 256)
        y[d] = g[d] * (x[d] - mean) * inv + b[d];
}

// ---------------------------------------------------------------------------
// Final softmax over the SEQUENCE axis (axis=1 of [B,L,V], faithful bug),
// applied to batch 7's logits: out[l,v] = exp(z[l,v]-max_l)/sum_l exp(...)
// Thread per vocab column; reads coalesced across v.
// ---------------------------------------------------------------------------
__global__ __launch_bounds__(256) void col_softmax_kernel(
    const float* __restrict__ logits, float* __restrict__ out)
{
    int v = blockIdx.x * 256 + threadIdx.x;
    if (v >= VOCAB) return;
    float m = -INFINITY;
    for (int l = 0; l < SEQN; ++l)
        m = fmaxf(m, logits[(size_t)l * VOCAB + v]);
    float s = 0.0f;
    for (int l = 0; l < SEQN; ++l)
        s += __expf(logits[(size_t)l * VOCAB + v] - m);
    float inv = 1.0f / s;
    for (int l = 0; l < SEQN; ++l)
        out[(size_t)l * VOCAB + v] = __expf(logits[(size_t)l * VOCAB + v] - m) * inv;
}

// ---------------------------------------------------------------------------
static inline void launch_gemm(const float* A,
                               const float* B0, const float* B1, const float* B2,
                               const float* bias0, const float* bias1, const float* bias2,
                               float* C0, float* C1, float* C2,
                               int M, int N, int K, int relu, int z, hipStream_t s)
{
    dim3 grid(M / BM, (N + BN - 1) / BN, z);
    hipLaunchKernelGGL(gemm_bt_kernel, grid, dim3(256), 0, s,
                       A, B0, B1, B2, bias0, bias1, bias2, C0, C1, C2, M, N, K, relu);
}

extern "C" void kernel_launch(void* const* d_in, const int* in_sizes, int n_in,
                              void* d_out, int out_size, void* d_ws, size_t ws_size,
                              hipStream_t stream)
{
    const float* x_in   = (const float*)d_in[0];
    const float* ctx_in = (const float*)d_in[1];
    const float* Wq1 = (const float*)d_in[2];
    const float* Wk1 = (const float*)d_in[3];
    const float* Wv1 = (const float*)d_in[4];
    const float* Wo1 = (const float*)d_in[5];
    const float* Wq2 = (const float*)d_in[6];
    const float* Wk2 = (const float*)d_in[7];
    const float* Wv2 = (const float*)d_in[8];
    const float* Wo2 = (const float*)d_in[9];
    const float* W_ff1 = (const float*)d_in[10];
    const float* b_ff1 = (const float*)d_in[11];
    const float* W_ff2 = (const float*)d_in[12];
    const float* b_ff2 = (const float*)d_in[13];
    const float* g1  = (const float*)d_in[14];
    const float* be1 = (const float*)d_in[15];
    const float* g2  = (const float*)d_in[16];
    const float* be2 = (const float*)d_in[17];
    const float* g3  = (const float*)d_in[18];
    const float* be3 = (const float*)d_in[19];
    const float* W_lin = (const float*)d_in[20];
    const float* b_lin = (const float*)d_in[21];
    float* out = (float*)d_out;

    // workspace layout (floats)
    float* ws = (float*)d_ws;
    const size_t TOK = (size_t)SEQN * D_EMB;          // 262144
    float* X   = ws;                // current activations [128,2048]
    float* Qb  = X   + TOK;
    float* Kb  = Qb  + TOK;
    float* Vb  = Kb  + TOK;
    float* Att = Vb  + TOK;         // attention concat [128,2048]
    float* X2  = Att + TOK;         // pre-LN buffer
    float* K2  = X2  + TOK;         // cross-attn K (layer-invariant)
    float* V2  = K2  + TOK;
    float* H   = V2  + TOK;         // FFN hidden [128,8192]
    float* LG  = H   + (size_t)SEQN * DFF;  // logits [128,30000]

    const float* ctx7 = ctx_in + (size_t)7 * SEQN * D_EMB;

    // x = x[7] + PE
    hipLaunchKernelGGL(add_pe_kernel, dim3((SEQN * D_EMB) / 256), dim3(256), 0, stream,
                       x_in, X);

    // cross-attn K2,V2 once (weights shared across layers; context constant)
    launch_gemm(ctx7, Wk2, Wv2, Wv2, nullptr, nullptr, nullptr,
                K2, V2, V2, SEQN, D_EMB, D_EMB, 0, 2, stream);

    for (int layer = 0; layer < NLAYERS; ++layer) {
        // ---- self attention ----
        launch_gemm(X, Wq1, Wk1, Wv1, nullptr, nullptr, nullptr,
                    Qb, Kb, Vb, SEQN, D_EMB, D_EMB, 0, 3, stream);
        hipLaunchKernelGGL(attn_token_kernel, dim3(SEQN), dim3(128), 0, stream,
                           Qb, Kb, Vb, Att, 1);
        launch_gemm(Att, Wo1, Wo1, Wo1, nullptr, nullptr, nullptr,
                    X2, X2, X2, SEQN, D_EMB, D_EMB, 0, 1, stream);
        hipLaunchKernelGGL(layernorm_kernel, dim3(SEQN), dim3(256), 0, stream,
                           X2, g1, be1, X);

        // ---- cross attention ----
        launch_gemm(X, Wq2, Wq2, Wq2, nullptr, nullptr, nullptr,
                    Qb, Qb, Qb, SEQN, D_EMB, D_EMB, 0, 1, stream);
        hipLaunchKernelGGL(attn_token_kernel, dim3(SEQN), dim3(128), 0, stream,
                           Qb, K2, V2, Att, 0);
        launch_gemm(Att, Wo2, Wo2, Wo2, nullptr, nullptr, nullptr,
                    X2, X2, X2, SEQN, D_EMB, D_EMB, 0, 1, stream);
        hipLaunchKernelGGL(layernorm_kernel, dim3(SEQN), dim3(256), 0, stream,
                           X2, g2, be2, X);

        // ---- FFN ----
        launch_gemm(X, W_ff1, W_ff1, W_ff1, b_ff1, b_ff1, b_ff1,
                    H, H, H, SEQN, DFF, D_EMB, 1, 1, stream);
        launch_gemm(H, W_ff2, W_ff2, W_ff2, b_ff2, b_ff2, b_ff2,
                    X2, X2, X2, SEQN, D_EMB, DFF, 0, 1, stream);
        hipLaunchKernelGGL(layernorm_kernel, dim3(SEQN), dim3(256), 0, stream,
                           X2, g3, be3, X);
    }

    // logits = X @ W_lin^T + b_lin   [128, 30000]
    launch_gemm(X, W_lin, W_lin, W_lin, b_lin, b_lin, b_lin,
                LG, LG, LG, SEQN, VOCAB, D_EMB, 0, 1, stream);

    // softmax over sequence axis, batch 7 -> d_out [128, 30000]
    hipLaunchKernelGGL(col_softmax_kernel, dim3((VOCAB + 255) / 256), dim3(256), 0, stream,
                       LG, out);
}

// Round 2
// 2429.028 us; speedup vs baseline: 5.7479x; 5.7479x over previous
//
#include <hip/hip_runtime.h>
#include <hip/hip_bf16.h>
#include <math.h>

#define D_EMB 2048
#define NH 16
#define DK 128
#define SEQN 128
#define DFF 8192
#define VOCAB 30000
#define NLAYERS 6

typedef __attribute__((ext_vector_type(8))) short short8v;
typedef __attribute__((ext_vector_type(4))) float float4v;
typedef __hip_bfloat16 bf16;

#define GLOAD_LDS16(g, l)                                                      \
    __builtin_amdgcn_global_load_lds(                                          \
        (const __attribute__((address_space(1))) void*)(g),                    \
        (__attribute__((address_space(3))) void*)(l), 16, 0, 0)

// ---------------------------------------------------------------------------
// fp32 -> bf16 conversion, z-batched over up to 8 (src,dst) pairs.
// ---------------------------------------------------------------------------
struct CvtArgs {
    const float* src[8];
    bf16* dst[8];
};

__global__ __launch_bounds__(256) void cvt_kernel(CvtArgs args, int n4) {
    int i = blockIdx.x * 256 + threadIdx.x;
    if (i >= n4) return;
    const float4* s = (const float4*)args.src[blockIdx.z];
    float4 v = s[i];
    union { short4 s4; bf16 h[4]; } u;
    u.h[0] = __float2bfloat16(v.x);
    u.h[1] = __float2bfloat16(v.y);
    u.h[2] = __float2bfloat16(v.z);
    u.h[3] = __float2bfloat16(v.w);
    ((short4*)args.dst[blockIdx.z])[i] = u.s4;
}

// ---------------------------------------------------------------------------
// x[7] + sinusoidal PE -> X [128,2048] bf16
// ---------------------------------------------------------------------------
__global__ __launch_bounds__(256) void add_pe_kernel(const float* __restrict__ x,
                                                     bf16* __restrict__ out) {
    int idx = blockIdx.x * 256 + threadIdx.x;
    int l = idx >> 11;
    int d = idx & 2047;
    float two_i = (float)(d & ~1);
    float div = __expf(-9.210340371976184f * two_i * (1.0f / 2048.0f));
    float ang = (float)l * div;
    float pe = (d & 1) ? cosf(ang) : sinf(ang);
    out[idx] = __float2bfloat16(x[(size_t)7 * SEQN * D_EMB + idx] + pe);
}

// ---------------------------------------------------------------------------
// bf16 MFMA GEMM: C[M,N] = A[M,K] @ B[N,K]^T (+bias)(+relu)
// Tile 64x64x64, 256 threads = 4 waves (2x2 of 32x32 per wave),
// mfma_f32_16x16x32_bf16, global_load_lds width-16 staging,
// XOR-swizzled LDS: phys_slot = log_slot ^ (row & 7)  (conflict-free b128).
// blockIdx.z selects among up to 3 (B, bias, C) sets.
// ---------------------------------------------------------------------------
__global__ __launch_bounds__(256) void gemm_mfma_kernel(
    const bf16* __restrict__ A,
    const bf16* B0, const bf16* B1, const bf16* B2,
    const float* bias0, const float* bias1, const float* bias2,
    void* C0, void* C1, void* C2,
    int M, int N, int K, int relu, int out_bf16)
{
    const bf16* B    = (blockIdx.z == 0) ? B0    : (blockIdx.z == 1) ? B1    : B2;
    const float* bias = (blockIdx.z == 0) ? bias0 : (blockIdx.z == 1) ? bias1 : bias2;
    void* C          = (blockIdx.z == 0) ? C0    : (blockIdx.z == 1) ? C1    : C2;

    __shared__ __align__(16) bf16 As[64 * 64];
    __shared__ __align__(16) bf16 Bs[64 * 64];

    int tid = threadIdx.x;
    int w = tid >> 6;
    int lane = tid & 63;
    int m0 = blockIdx.x * 64;
    int n0 = blockIdx.y * 64;
    int wm = (w & 1) * 32;
    int wn = (w >> 1) * 32;

    // staging coords (per issue t: row = t*32 + w*8 + (lane>>3), slot = lane&7)
    int rW = w * 8 + (lane >> 3);
    int sp = lane & 7;

    // fragment read offsets (bytes into As/Bs), per kk and frag index
    int fcol = lane & 15;
    int fqu  = lane >> 4;   // 0..3

    float4v acc[2][2];
    acc[0][0] = (float4v)0.0f; acc[0][1] = (float4v)0.0f;
    acc[1][0] = (float4v)0.0f; acc[1][1] = (float4v)0.0f;

    for (int k0 = 0; k0 < K; k0 += 64) {
        // ---- stage A and B tiles (2 issues each per wave) ----
        #pragma unroll
        for (int t = 0; t < 2; ++t) {
            int r = t * 32 + rW;
            int sl = sp ^ (r & 7);
            char* ldsA = (char*)As + (size_t)(t * 32 + w * 8) * 128;
            const bf16* ga = A + (size_t)(m0 + r) * K + k0 + sl * 8;
            GLOAD_LDS16(ga, ldsA);
            int gn = n0 + r;
            char* ldsB = (char*)Bs + (size_t)(t * 32 + w * 8) * 128;
            if (gn < N) {
                const bf16* gb = B + (size_t)gn * K + k0 + sl * 8;
                GLOAD_LDS16(gb, ldsB);
            }
        }
        __syncthreads();

        // ---- MFMA over the 64-deep K tile (2 steps of 32) ----
        #pragma unroll
        for (int kk = 0; kk < 2; ++kk) {
            short8v a[2], b[2];
            int slog = kk * 4 + fqu;
            #pragma unroll
            for (int fm = 0; fm < 2; ++fm) {
                int m = wm + fm * 16 + fcol;
                int off = m * 128 + ((slog ^ (m & 7)) * 16);
                a[fm] = *(const short8v*)((const char*)As + off);
            }
            #pragma unroll
            for (int fn = 0; fn < 2; ++fn) {
                int n = wn + fn * 16 + fcol;
                int off = n * 128 + ((slog ^ (n & 7)) * 16);
                b[fn] = *(const short8v*)((const char*)Bs + off);
            }
            #pragma unroll
            for (int fm = 0; fm < 2; ++fm)
                #pragma unroll
                for (int fn = 0; fn < 2; ++fn)
                    acc[fm][fn] = __builtin_amdgcn_mfma_f32_16x16x32_bf16(
                        a[fm], b[fn], acc[fm][fn], 0, 0, 0);
        }
        __syncthreads();
    }

    // ---- epilogue: C[row = (lane>>4)*4 + reg, col = lane&15] ----
    int rbase = fqu * 4;
    #pragma unroll
    for (int fm = 0; fm < 2; ++fm) {
        #pragma unroll
        for (int fn = 0; fn < 2; ++fn) {
            int n = n0 + wn + fn * 16 + fcol;
            if (n >= N) continue;
            float bv = bias ? bias[n] : 0.0f;
            #pragma unroll
            for (int r = 0; r < 4; ++r) {
                int m = m0 + wm + fm * 16 + rbase + r;
                float v = acc[fm][fn][r] + bv;
                if (relu) v = fmaxf(v, 0.0f);
                if (out_bf16)
                    ((bf16*)C)[(size_t)m * N + n] = __float2bfloat16(v);
                else
                    ((float*)C)[(size_t)m * N + n] = v;
            }
        }
    }
}

// ---------------------------------------------------------------------------
// Per-token "attention" (faithful bug): token l attends over the d_k axis.
// One block (128 threads) per token; thread i owns score-row i.
// ---------------------------------------------------------------------------
__global__ __launch_bounds__(128) void attn_token_kernel(
    const bf16* __restrict__ Q, const bf16* __restrict__ K,
    const bf16* __restrict__ V, bf16* __restrict__ O, int causal)
{
    int l = blockIdx.x;
    int i = threadIdx.x;
    __shared__ float qs[D_EMB];
    __shared__ float ks[D_EMB];
    __shared__ float vs[D_EMB];
    for (int d = i; d < D_EMB; d += 128) {
        qs[d] = (float)Q[(size_t)l * D_EMB + d];
        ks[d] = (float)K[(size_t)l * D_EMB + d];
        vs[d] = (float)V[(size_t)l * D_EMB + d];
    }
    __syncthreads();

    const float scale = 0.088388347648318447f;  // 1/sqrt(128)
    float qr[NH];
    #pragma unroll
    for (int h = 0; h < NH; ++h) qr[h] = qs[h * DK + i];

    int jmax = causal ? (i + 1) : DK;

    float m = -INFINITY, lsum = 0.0f;
    for (int j = 0; j < jmax; ++j) {
        float s = 0.0f;
        #pragma unroll
        for (int h = 0; h < NH; ++h) s += qr[h] * ks[h * DK + j];
        s *= scale;
        float nm = fmaxf(m, s);
        lsum = lsum * __expf(m - nm) + __expf(s - nm);
        m = nm;
    }
    float rinv = 1.0f / lsum;

    float acc[NH];
    #pragma unroll
    for (int h = 0; h < NH; ++h) acc[h] = 0.0f;
    for (int j = 0; j < jmax; ++j) {
        float s = 0.0f;
        #pragma unroll
        for (int h = 0; h < NH; ++h) s += qr[h] * ks[h * DK + j];
        float p = __expf(s * scale - m) * rinv;
        #pragma unroll
        for (int h = 0; h < NH; ++h) acc[h] += p * vs[h * DK + j];
    }
    #pragma unroll
    for (int h = 0; h < NH; ++h)
        O[(size_t)l * D_EMB + h * DK + i] = __float2bfloat16(acc[h]);
}

// ---------------------------------------------------------------------------
// Row LayerNorm over 2048, bf16 in/out, fp32 math.
// ---------------------------------------------------------------------------
__global__ __launch_bounds__(256) void layernorm_kernel(
    const bf16* __restrict__ X, const float* __restrict__ g,
    const float* __restrict__ b, bf16* __restrict__ Y)
{
    int row = blockIdx.x;
    const bf16* x = X + (size_t)row * D_EMB;
    bf16* y = Y + (size_t)row * D_EMB;
    __shared__ float buf[256];
    int tid = threadIdx.x;

    float s = 0.0f;
    for (int d = tid; d < D_EMB; d += 256) s += (float)x[d];
    buf[tid] = s; __syncthreads();
    for (int off = 128; off; off >>= 1) {
        if (tid < off) buf[tid] += buf[tid + off];
        __syncthreads();
    }
    float mean = buf[0] * (1.0f / D_EMB);
    __syncthreads();

    float vsum = 0.0f;
    for (int d = tid; d < D_EMB; d += 256) {
        float t = (float)x[d] - mean;
        vsum += t * t;
    }
    buf[tid] = vsum; __syncthreads();
    for (int off = 128; off; off >>= 1) {
        if (tid < off) buf[tid] += buf[tid + off];
        __syncthreads();
    }
    float inv = rsqrtf(buf[0] * (1.0f / D_EMB) + 1e-5f);

    for (int d = tid; d < D_EMB; d += 256)
        y[d] = __float2bfloat16(g[d] * ((float)x[d] - mean) * inv + b[d]);
}

// ---------------------------------------------------------------------------
// Final softmax over the sequence axis (faithful bug), logits fp32 -> out fp32.
// ---------------------------------------------------------------------------
__global__ __launch_bounds__(256) void col_softmax_kernel(
    const float* __restrict__ logits, float* __restrict__ out)
{
    int v = blockIdx.x * 256 + threadIdx.x;
    if (v >= VOCAB) return;
    float m = -INFINITY;
    for (int l = 0; l < SEQN; ++l)
        m = fmaxf(m, logits[(size_t)l * VOCAB + v]);
    float s = 0.0f;
    for (int l = 0; l < SEQN; ++l)
        s += __expf(logits[(size_t)l * VOCAB + v] - m);
    float inv = 1.0f / s;
    for (int l = 0; l < SEQN; ++l)
        out[(size_t)l * VOCAB + v] = __expf(logits[(size_t)l * VOCAB + v] - m) * inv;
}

// ---------------------------------------------------------------------------
static inline void launch_gemm(const bf16* A,
                               const bf16* B0, const bf16* B1, const bf16* B2,
                               const float* bias0, const float* bias1, const float* bias2,
                               void* C0, void* C1, void* C2,
                               int M, int N, int K, int relu, int out_bf16, int z,
                               hipStream_t s)
{
    dim3 grid(M / 64, (N + 63) / 64, z);
    hipLaunchKernelGGL(gemm_mfma_kernel, grid, dim3(256), 0, s,
                       A, B0, B1, B2, bias0, bias1, bias2, C0, C1, C2,
                       M, N, K, relu, out_bf16);
}

extern "C" void kernel_launch(void* const* d_in, const int* in_sizes, int n_in,
                              void* d_out, int out_size, void* d_ws, size_t ws_size,
                              hipStream_t stream)
{
    const float* x_in   = (const float*)d_in[0];
    const float* ctx_in = (const float*)d_in[1];
    const float* Wq1 = (const float*)d_in[2];
    const float* Wk1 = (const float*)d_in[3];
    const float* Wv1 = (const float*)d_in[4];
    const float* Wo1 = (const float*)d_in[5];
    const float* Wq2 = (const float*)d_in[6];
    const float* Wk2 = (const float*)d_in[7];
    const float* Wv2 = (const float*)d_in[8];
    const float* Wo2 = (const float*)d_in[9];
    const float* W_ff1 = (const float*)d_in[10];
    const float* b_ff1 = (const float*)d_in[11];
    const float* W_ff2 = (const float*)d_in[12];
    const float* b_ff2 = (const float*)d_in[13];
    const float* g1  = (const float*)d_in[14];
    const float* be1 = (const float*)d_in[15];
    const float* g2  = (const float*)d_in[16];
    const float* be2 = (const float*)d_in[17];
    const float* g3  = (const float*)d_in[18];
    const float* be3 = (const float*)d_in[19];
    const float* W_lin = (const float*)d_in[20];
    const float* b_lin = (const float*)d_in[21];
    float* out = (float*)d_out;

    // ---- workspace layout (bytes; every size is a multiple of 256) ----
    const size_t W2  = (size_t)D_EMB * D_EMB;     // 4,194,304
    const size_t WF  = (size_t)DFF * D_EMB;       // 16,777,216
    const size_t WL  = (size_t)VOCAB * D_EMB;     // 61,440,000
    const size_t TOK = (size_t)SEQN * D_EMB;      // 262,144

    char* p = (char*)d_ws;
    bf16* wq1 = (bf16*)p; p += W2 * 2;
    bf16* wk1 = (bf16*)p; p += W2 * 2;
    bf16* wv1 = (bf16*)p; p += W2 * 2;
    bf16* wo1 = (bf16*)p; p += W2 * 2;
    bf16* wq2 = (bf16*)p; p += W2 * 2;
    bf16* wk2 = (bf16*)p; p += W2 * 2;
    bf16* wv2 = (bf16*)p; p += W2 * 2;
    bf16* wo2 = (bf16*)p; p += W2 * 2;
    bf16* wff1 = (bf16*)p; p += WF * 2;
    bf16* wff2 = (bf16*)p; p += WF * 2;
    bf16* wlin = (bf16*)p; p += WL * 2;
    bf16* wctx = (bf16*)p; p += TOK * 2;
    bf16* X   = (bf16*)p; p += TOK * 2;
    bf16* Qb  = (bf16*)p; p += TOK * 2;
    bf16* Kb  = (bf16*)p; p += TOK * 2;
    bf16* Vb  = (bf16*)p; p += TOK * 2;
    bf16* Att = (bf16*)p; p += TOK * 2;
    bf16* X2  = (bf16*)p; p += TOK * 2;
    bf16* K2  = (bf16*)p; p += TOK * 2;
    bf16* V2  = (bf16*)p; p += TOK * 2;
    bf16* H   = (bf16*)p; p += (size_t)SEQN * DFF * 2;
    float* LG = (float*)p; p += (size_t)SEQN * VOCAB * 4;

    const float* ctx7 = ctx_in + (size_t)7 * SEQN * D_EMB;

    // ---- weight conversion fp32 -> bf16 (3 batched dispatches + ctx) ----
    {
        CvtArgs a = {};
        a.src[0] = Wq1; a.dst[0] = wq1;
        a.src[1] = Wk1; a.dst[1] = wk1;
        a.src[2] = Wv1; a.dst[2] = wv1;
        a.src[3] = Wo1; a.dst[3] = wo1;
        a.src[4] = Wq2; a.dst[4] = wq2;
        a.src[5] = Wk2; a.dst[5] = wk2;
        a.src[6] = Wv2; a.dst[6] = wv2;
        a.src[7] = Wo2; a.dst[7] = wo2;
        int n4 = (int)(W2 / 4);
        hipLaunchKernelGGL(cvt_kernel, dim3((n4 + 255) / 256, 1, 8), dim3(256), 0,
                           stream, a, n4);
    }
    {
        CvtArgs a = {};
        a.src[0] = W_ff1; a.dst[0] = wff1;
        a.src[1] = W_ff2; a.dst[1] = wff2;
        int n4 = (int)(WF / 4);
        hipLaunchKernelGGL(cvt_kernel, dim3((n4 + 255) / 256, 1, 2), dim3(256), 0,
                           stream, a, n4);
    }
    {
        CvtArgs a = {};
        a.src[0] = W_lin; a.dst[0] = wlin;
        int n4 = (int)(WL / 4);
        hipLaunchKernelGGL(cvt_kernel, dim3((n4 + 255) / 256, 1, 1), dim3(256), 0,
                           stream, a, n4);
    }
    {
        CvtArgs a = {};
        a.src[0] = ctx7; a.dst[0] = wctx;
        int n4 = (int)(TOK / 4);
        hipLaunchKernelGGL(cvt_kernel, dim3((n4 + 255) / 256, 1, 1), dim3(256), 0,
                           stream, a, n4);
    }

    // x = x[7] + PE
    hipLaunchKernelGGL(add_pe_kernel, dim3((SEQN * D_EMB) / 256), dim3(256), 0,
                       stream, x_in, X);

    // cross-attn K2, V2 once (weights shared, context constant)
    launch_gemm(wctx, wk2, wv2, wv2, nullptr, nullptr, nullptr,
                K2, V2, V2, SEQN, D_EMB, D_EMB, 0, 1, 2, stream);

    for (int layer = 0; layer < NLAYERS; ++layer) {
        // ---- self attention ----
        launch_gemm(X, wq1, wk1, wv1, nullptr, nullptr, nullptr,
                    Qb, Kb, Vb, SEQN, D_EMB, D_EMB, 0, 1, 3, stream);
        hipLaunchKernelGGL(attn_token_kernel, dim3(SEQN), dim3(128), 0, stream,
                           Qb, Kb, Vb, Att, 1);
        launch_gemm(Att, wo1, wo1, wo1, nullptr, nullptr, nullptr,
                    X2, X2, X2, SEQN, D_EMB, D_EMB, 0, 1, 1, stream);
        hipLaunchKernelGGL(layernorm_kernel, dim3(SEQN), dim3(256), 0, stream,
                           X2, g1, be1, X);

        // ---- cross attention ----
        launch_gemm(X, wq2, wq2, wq2, nullptr, nullptr, nullptr,
                    Qb, Qb, Qb, SEQN, D_EMB, D_EMB, 0, 1, 1, stream);
        hipLaunchKernelGGL(attn_token_kernel, dim3(SEQN), dim3(128), 0, stream,
                           Qb, K2, V2, Att, 0);
        launch_gemm(Att, wo2, wo2, wo2, nullptr, nullptr, nullptr,
                    X2, X2, X2, SEQN, D_EMB, D_EMB, 0, 1, 1, stream);
        hipLaunchKernelGGL(layernorm_kernel, dim3(SEQN), dim3(256), 0, stream,
                           X2, g2, be2, X);

        // ---- FFN ----
        launch_gemm(X, wff1, wff1, wff1, b_ff1, b_ff1, b_ff1,
                    H, H, H, SEQN, DFF, D_EMB, 1, 1, 1, stream);
        launch_gemm(H, wff2, wff2, wff2, b_ff2, b_ff2, b_ff2,
                    X2, X2, X2, SEQN, D_EMB, DFF, 0, 1, 1, stream);
        hipLaunchKernelGGL(layernorm_kernel, dim3(SEQN), dim3(256), 0, stream,
                           X2, g3, be3, X);
    }

    // logits = X @ W_lin^T + b_lin  (fp32 out)
    launch_gemm(X, wlin, wlin, wlin, b_lin, b_lin, b_lin,
                LG, LG, LG, SEQN, VOCAB, D_EMB, 0, 0, 1, stream);

    // softmax over sequence axis -> d_out [128, 30000]
    hipLaunchKernelGGL(col_softmax_kernel, dim3((VOCAB + 255) / 256), dim3(256), 0,
                       stream, LG, out);
}

// Round 3
// 1837.123 us; speedup vs baseline: 7.5999x; 1.3222x over previous
//
#include <hip/hip_runtime.h>
#include <hip/hip_bf16.h>
#include <math.h>

#define D_EMB 2048
#define NH 16
#define DK 128
#define SEQN 128
#define DFF 8192
#define VOCAB 30000
#define NLAYERS 6
#define TOKF (SEQN * D_EMB)   // 262144 elements

typedef __attribute__((ext_vector_type(8))) short short8v;
typedef __attribute__((ext_vector_type(4))) float float4v;
typedef __hip_bfloat16 bf16;

#define GLOAD_LDS16(g, l)                                                      \
    __builtin_amdgcn_global_load_lds(                                          \
        (const __attribute__((address_space(1))) void*)(g),                    \
        (__attribute__((address_space(3))) void*)(l), 16, 0, 0)

// ---------------------------------------------------------------------------
// fp32 -> bf16 conversion, z-batched over up to 8 (src,dst) pairs.
// ---------------------------------------------------------------------------
struct CvtArgs {
    const float* src[8];
    bf16* dst[8];
};

__global__ __launch_bounds__(256) void cvt_kernel(CvtArgs args, int n4) {
    int i = blockIdx.x * 256 + threadIdx.x;
    if (i >= n4) return;
    const float4* s = (const float4*)args.src[blockIdx.z];
    float4 v = s[i];
    union { short4 s4; bf16 h[4]; } u;
    u.h[0] = __float2bfloat16(v.x);
    u.h[1] = __float2bfloat16(v.y);
    u.h[2] = __float2bfloat16(v.z);
    u.h[3] = __float2bfloat16(v.w);
    ((short4*)args.dst[blockIdx.z])[i] = u.s4;
}

// ---------------------------------------------------------------------------
// x[7] + sinusoidal PE -> X [128,2048] bf16
// ---------------------------------------------------------------------------
__global__ __launch_bounds__(256) void add_pe_kernel(const float* __restrict__ x,
                                                     bf16* __restrict__ out) {
    int idx = blockIdx.x * 256 + threadIdx.x;
    int l = idx >> 11;
    int d = idx & 2047;
    float two_i = (float)(d & ~1);
    float div = __expf(-9.210340371976184f * two_i * (1.0f / 2048.0f));
    float ang = (float)l * div;
    float pe = (d & 1) ? cosf(ang) : sinf(ang);
    out[idx] = __float2bfloat16(x[(size_t)7 * SEQN * D_EMB + idx] + pe);
}

// ---------------------------------------------------------------------------
// bf16 MFMA GEMM: C = A[M,K] @ B[N,K]^T, tile 64x64, BK=128, 4 waves,
// mfma_f32_16x16x32_bf16, global_load_lds width-16, XOR-16 LDS swizzle.
// blockIdx.z = oi*ksplit + kh: oi selects (B,bias,C) set, kh the K-half.
// out_bf16=1: bf16 C with bias/relu. out_bf16=0: fp32 partial at C+kh*M*N.
// N must be a multiple of 64, K/ksplit a multiple of 128.
// ---------------------------------------------------------------------------
__global__ __launch_bounds__(256) void gemm_mfma_kernel(
    const bf16* __restrict__ A,
    const bf16* B0, const bf16* B1, const bf16* B2,
    const float* bias0, const float* bias1, const float* bias2,
    void* C0, void* C1, void* C2,
    int M, int N, int K, int relu, int out_bf16, int ksplit)
{
    int z = blockIdx.z;
    int oi = (ksplit == 1) ? z : (z >> 1);
    int kh = (ksplit == 1) ? 0 : (z & 1);
    int Klocal = K / ksplit;
    int kbase = kh * Klocal;

    const bf16* B    = (oi == 0) ? B0    : (oi == 1) ? B1    : B2;
    const float* bias = (oi == 0) ? bias0 : (oi == 1) ? bias1 : bias2;
    void* C          = (oi == 0) ? C0    : (oi == 1) ? C1    : C2;

    __shared__ __align__(16) bf16 As[64 * 128];   // 16 KB
    __shared__ __align__(16) bf16 Bs[64 * 128];   // 16 KB

    int tid = threadIdx.x;
    int w = tid >> 6;
    int lane = tid & 63;
    int m0 = blockIdx.x * 64;
    int n0 = blockIdx.y * 64;
    int wm = (w & 1) * 32;
    int wn = (w >> 1) * 32;
    int fcol = lane & 15;
    int fqu  = lane >> 4;

    float4v acc[2][2];
    acc[0][0] = (float4v)0.0f; acc[0][1] = (float4v)0.0f;
    acc[1][0] = (float4v)0.0f; acc[1][1] = (float4v)0.0f;

    for (int k0 = 0; k0 < Klocal; k0 += 128) {
        #pragma unroll
        for (int t = 0; t < 4; ++t) {
            int r = t * 16 + (w << 2) + (lane >> 4);
            int s = (lane & 15) ^ (r & 15);
            const bf16* ga = A + (size_t)(m0 + r) * K + kbase + k0 + s * 8;
            GLOAD_LDS16(ga, (char*)As + (size_t)(t * 16 + (w << 2)) * 256);
            const bf16* gb = B + (size_t)(n0 + r) * K + kbase + k0 + s * 8;
            GLOAD_LDS16(gb, (char*)Bs + (size_t)(t * 16 + (w << 2)) * 256);
        }
        __syncthreads();

        #pragma unroll
        for (int kk = 0; kk < 4; ++kk) {
            short8v a[2], b[2];
            int slog = kk * 4 + fqu;
            #pragma unroll
            for (int fm = 0; fm < 2; ++fm) {
                int m = wm + fm * 16 + fcol;
                a[fm] = *(const short8v*)((const char*)As + m * 256 + ((slog ^ (m & 15)) << 4));
            }
            #pragma unroll
            for (int fn = 0; fn < 2; ++fn) {
                int n = wn + fn * 16 + fcol;
                b[fn] = *(const short8v*)((const char*)Bs + n * 256 + ((slog ^ (n & 15)) << 4));
            }
            #pragma unroll
            for (int fm = 0; fm < 2; ++fm)
                #pragma unroll
                for (int fn = 0; fn < 2; ++fn)
                    acc[fm][fn] = __builtin_amdgcn_mfma_f32_16x16x32_bf16(
                        a[fm], b[fn], acc[fm][fn], 0, 0, 0);
        }
        __syncthreads();
    }

    int rbase = fqu * 4;
    #pragma unroll
    for (int fm = 0; fm < 2; ++fm) {
        #pragma unroll
        for (int fn = 0; fn < 2; ++fn) {
            int n = n0 + wn + fn * 16 + fcol;
            #pragma unroll
            for (int r = 0; r < 4; ++r) {
                int m = m0 + wm + fm * 16 + rbase + r;
                float v = acc[fm][fn][r];
                if (out_bf16) {
                    v += bias ? bias[n] : 0.0f;
                    if (relu) v = fmaxf(v, 0.0f);
                    ((bf16*)C)[(size_t)m * N + n] = __float2bfloat16(v);
                } else {
                    ((float*)C)[(size_t)kh * M * N + (size_t)m * N + n] = v;
                }
            }
        }
    }
}

// ---------------------------------------------------------------------------
// Per-token "attention" (faithful bug). Q from fp32 split-K partial pair;
// K/V either fp32 partial pairs (self) or bf16 single (cross, precomputed).
// ---------------------------------------------------------------------------
__global__ __launch_bounds__(128) void attn_token_kernel(
    const float* __restrict__ qa, const float* __restrict__ qb,
    const float* __restrict__ ka, const float* __restrict__ kb,
    const float* __restrict__ va, const float* __restrict__ vb,
    const bf16* __restrict__ k16, const bf16* __restrict__ v16,
    bf16* __restrict__ O, int causal, int kv16)
{
    int l = blockIdx.x;
    int i = threadIdx.x;
    __shared__ float qs[D_EMB];
    __shared__ float ks[D_EMB];
    __shared__ float vs[D_EMB];
    size_t base = (size_t)l * D_EMB;
    for (int d = i; d < D_EMB; d += 128) {
        qs[d] = qa[base + d] + qb[base + d];
        if (kv16) {
            ks[d] = (float)k16[base + d];
            vs[d] = (float)v16[base + d];
        } else {
            ks[d] = ka[base + d] + kb[base + d];
            vs[d] = va[base + d] + vb[base + d];
        }
    }
    __syncthreads();

    const float scale = 0.088388347648318447f;  // 1/sqrt(128)
    float qr[NH];
    #pragma unroll
    for (int h = 0; h < NH; ++h) qr[h] = qs[h * DK + i];

    int jmax = causal ? (i + 1) : DK;

    float m = -INFINITY, lsum = 0.0f;
    for (int j = 0; j < jmax; ++j) {
        float s = 0.0f;
        #pragma unroll
        for (int h = 0; h < NH; ++h) s += qr[h] * ks[h * DK + j];
        s *= scale;
        float nm = fmaxf(m, s);
        lsum = lsum * __expf(m - nm) + __expf(s - nm);
        m = nm;
    }
    float rinv = 1.0f / lsum;

    float acc[NH];
    #pragma unroll
    for (int h = 0; h < NH; ++h) acc[h] = 0.0f;
    for (int j = 0; j < jmax; ++j) {
        float s = 0.0f;
        #pragma unroll
        for (int h = 0; h < NH; ++h) s += qr[h] * ks[h * DK + j];
        float p = __expf(s * scale - m) * rinv;
        #pragma unroll
        for (int h = 0; h < NH; ++h) acc[h] += p * vs[h * DK + j];
    }
    #pragma unroll
    for (int h = 0; h < NH; ++h)
        O[base + h * DK + i] = __float2bfloat16(acc[h]);
}

// ---------------------------------------------------------------------------
// LayerNorm on (pa + pb + optional bias), fp32 in (split-K partials), bf16 out.
// ---------------------------------------------------------------------------
__global__ __launch_bounds__(256) void layernorm_kernel(
    const float* __restrict__ pa, const float* __restrict__ pb,
    const float* __restrict__ addb,
    const float* __restrict__ g, const float* __restrict__ b,
    bf16* __restrict__ Y)
{
    int row = blockIdx.x;
    size_t base = (size_t)row * D_EMB;
    __shared__ float vs[D_EMB];
    __shared__ float buf[256];
    int tid = threadIdx.x;

    float s = 0.0f;
    for (int d = tid; d < D_EMB; d += 256) {
        float v = pa[base + d] + pb[base + d] + (addb ? addb[d] : 0.0f);
        vs[d] = v;
        s += v;
    }
    buf[tid] = s; __syncthreads();
    for (int off = 128; off; off >>= 1) {
        if (tid < off) buf[tid] += buf[tid + off];
        __syncthreads();
    }
    float mean = buf[0] * (1.0f / D_EMB);
    __syncthreads();

    float vsum = 0.0f;
    for (int d = tid; d < D_EMB; d += 256) {
        float t = vs[d] - mean;
        vsum += t * t;
    }
    buf[tid] = vsum; __syncthreads();
    for (int off = 128; off; off >>= 1) {
        if (tid < off) buf[tid] += buf[tid + off];
        __syncthreads();
    }
    float inv = rsqrtf(buf[0] * (1.0f / D_EMB) + 1e-5f);

    for (int d = tid; d < D_EMB; d += 256)
        Y[base + d] = __float2bfloat16(g[d] * (vs[d] - mean) * inv + b[d]);
}

// ---------------------------------------------------------------------------
// Fused logits GEMM + softmax over the sequence axis (axis=1, faithful bug).
// Full-M tile: block = [128 rows x 64 vocab cols], K=2048. W read as fp32 and
// converted in-register (saves the wlin cvt pass). b_lin cancels in softmax.
// 4 waves; wave w owns rows w*32..w*32+31 (2 m-frags x 4 n-frags of 16x16).
// ---------------------------------------------------------------------------
__global__ __launch_bounds__(256) void logits_softmax_kernel(
    const bf16* __restrict__ X, const float* __restrict__ W,
    float* __restrict__ out)
{
    __shared__ __align__(16) bf16 As[128 * 128];   // 32 KB
    __shared__ __align__(16) bf16 Bs[64 * 128];    // 16 KB
    __shared__ float red[4][64];

    int tid = threadIdx.x;
    int w = tid >> 6;
    int lane = tid & 63;
    int fcol = lane & 15;
    int fqu  = lane >> 4;
    int n0 = blockIdx.x * 64;

    float4v acc[2][4];
    #pragma unroll
    for (int fm = 0; fm < 2; ++fm)
        #pragma unroll
        for (int fn = 0; fn < 4; ++fn) acc[fm][fn] = (float4v)0.0f;

    int brow = tid >> 2;          // 0..63
    int q    = tid & 3;
    int gn   = n0 + brow;

    for (int k0 = 0; k0 < D_EMB; k0 += 128) {
        // stage A (bf16, direct-to-LDS)
        #pragma unroll
        for (int t = 0; t < 8; ++t) {
            int r = t * 16 + (w << 2) + (lane >> 4);
            int s = (lane & 15) ^ (r & 15);
            GLOAD_LDS16(X + (size_t)r * D_EMB + k0 + s * 8,
                        (char*)As + (size_t)(t * 16 + (w << 2)) * 256);
        }
        // stage B (fp32 -> bf16 in-register)
        #pragma unroll
        for (int j = 0; j < 4; ++j) {
            int sL = q * 4 + j;
            union { short8v v; bf16 h[8]; } u;
            if (gn < VOCAB) {
                const float* gp = W + (size_t)gn * D_EMB + k0 + sL * 8;
                float4 f0 = *(const float4*)gp;
                float4 f1 = *(const float4*)(gp + 4);
                u.h[0] = __float2bfloat16(f0.x); u.h[1] = __float2bfloat16(f0.y);
                u.h[2] = __float2bfloat16(f0.z); u.h[3] = __float2bfloat16(f0.w);
                u.h[4] = __float2bfloat16(f1.x); u.h[5] = __float2bfloat16(f1.y);
                u.h[6] = __float2bfloat16(f1.z); u.h[7] = __float2bfloat16(f1.w);
            } else {
                u.v = (short8v)0;
            }
            *(short8v*)((char*)Bs + brow * 256 + ((sL ^ (brow & 15)) << 4)) = u.v;
        }
        __syncthreads();

        #pragma unroll
        for (int kk = 0; kk < 4; ++kk) {
            int slog = kk * 4 + fqu;
            short8v a[2], b[4];
            #pragma unroll
            for (int fm = 0; fm < 2; ++fm) {
                int m = w * 32 + fm * 16 + fcol;
                a[fm] = *(const short8v*)((const char*)As + m * 256 + ((slog ^ (m & 15)) << 4));
            }
            #pragma unroll
            for (int fn = 0; fn < 4; ++fn) {
                int n = fn * 16 + fcol;
                b[fn] = *(const short8v*)((const char*)Bs + n * 256 + ((slog ^ (n & 15)) << 4));
            }
            #pragma unroll
            for (int fm = 0; fm < 2; ++fm)
                #pragma unroll
                for (int fn = 0; fn < 4; ++fn)
                    acc[fm][fn] = __builtin_amdgcn_mfma_f32_16x16x32_bf16(
                        a[fm], b[fn], acc[fm][fn], 0, 0, 0);
        }
        __syncthreads();
    }

    // ---- column max over 128 rows ----
    float cmax[4];
    #pragma unroll
    for (int fn = 0; fn < 4; ++fn) {
        float m = -INFINITY;
        #pragma unroll
        for (int fm = 0; fm < 2; ++fm)
            #pragma unroll
            for (int r = 0; r < 4; ++r) m = fmaxf(m, acc[fm][fn][r]);
        m = fmaxf(m, __shfl_xor(m, 16));
        m = fmaxf(m, __shfl_xor(m, 32));
        cmax[fn] = m;
    }
    if (lane < 16) {
        #pragma unroll
        for (int fn = 0; fn < 4; ++fn) red[w][fn * 16 + lane] = cmax[fn];
    }
    __syncthreads();
    #pragma unroll
    for (int fn = 0; fn < 4; ++fn) {
        float m = red[0][fn * 16 + fcol];
        m = fmaxf(m, red[1][fn * 16 + fcol]);
        m = fmaxf(m, red[2][fn * 16 + fcol]);
        m = fmaxf(m, red[3][fn * 16 + fcol]);
        cmax[fn] = m;
    }
    __syncthreads();

    // ---- exp + column sum ----
    float csum[4];
    #pragma unroll
    for (int fn = 0; fn < 4; ++fn) {
        float s = 0.0f;
        #pragma unroll
        for (int fm = 0; fm < 2; ++fm)
            #pragma unroll
            for (int r = 0; r < 4; ++r) {
                float e = __expf(acc[fm][fn][r] - cmax[fn]);
                acc[fm][fn][r] = e;
                s += e;
            }
        s += __shfl_xor(s, 16);
        s += __shfl_xor(s, 32);
        csum[fn] = s;
    }
    if (lane < 16) {
        #pragma unroll
        for (int fn = 0; fn < 4; ++fn) red[w][fn * 16 + lane] = csum[fn];
    }
    __syncthreads();
    #pragma unroll
    for (int fn = 0; fn < 4; ++fn) {
        float s = red[0][fn * 16 + fcol] + red[1][fn * 16 + fcol]
                + red[2][fn * 16 + fcol] + red[3][fn * 16 + fcol];
        float rinv = 1.0f / s;
        int c = n0 + fn * 16 + fcol;
        if (c < VOCAB) {
            #pragma unroll
            for (int fm = 0; fm < 2; ++fm)
                #pragma unroll
                for (int r = 0; r < 4; ++r) {
                    int rw = w * 32 + fm * 16 + fqu * 4 + r;
                    out[(size_t)rw * VOCAB + c] = acc[fm][fn][r] * rinv;
                }
        }
    }
}

// ---------------------------------------------------------------------------
static inline void launch_gemm(const bf16* A,
                               const bf16* B0, const bf16* B1, const bf16* B2,
                               const float* bias0, const float* bias1, const float* bias2,
                               void* C0, void* C1, void* C2,
                               int M, int N, int K, int relu, int out_bf16,
                               int nout, int ksplit, hipStream_t s)
{
    dim3 grid(M / 64, N / 64, nout * ksplit);
    hipLaunchKernelGGL(gemm_mfma_kernel, grid, dim3(256), 0, s,
                       A, B0, B1, B2, bias0, bias1, bias2, C0, C1, C2,
                       M, N, K, relu, out_bf16, ksplit);
}

extern "C" void kernel_launch(void* const* d_in, const int* in_sizes, int n_in,
                              void* d_out, int out_size, void* d_ws, size_t ws_size,
                              hipStream_t stream)
{
    const float* x_in   = (const float*)d_in[0];
    const float* ctx_in = (const float*)d_in[1];
    const float* Wq1 = (const float*)d_in[2];
    const float* Wk1 = (const float*)d_in[3];
    const float* Wv1 = (const float*)d_in[4];
    const float* Wo1 = (const float*)d_in[5];
    const float* Wq2 = (const float*)d_in[6];
    const float* Wk2 = (const float*)d_in[7];
    const float* Wv2 = (const float*)d_in[8];
    const float* Wo2 = (const float*)d_in[9];
    const float* W_ff1 = (const float*)d_in[10];
    const float* b_ff1 = (const float*)d_in[11];
    const float* W_ff2 = (const float*)d_in[12];
    const float* b_ff2 = (const float*)d_in[13];
    const float* g1  = (const float*)d_in[14];
    const float* be1 = (const float*)d_in[15];
    const float* g2  = (const float*)d_in[16];
    const float* be2 = (const float*)d_in[17];
    const float* g3  = (const float*)d_in[18];
    const float* be3 = (const float*)d_in[19];
    const float* W_lin = (const float*)d_in[20];
    float* out = (float*)d_out;

    const size_t W2 = (size_t)D_EMB * D_EMB;
    const size_t WF = (size_t)DFF * D_EMB;

    char* p = (char*)d_ws;
    bf16* wq1 = (bf16*)p; p += W2 * 2;
    bf16* wk1 = (bf16*)p; p += W2 * 2;
    bf16* wv1 = (bf16*)p; p += W2 * 2;
    bf16* wo1 = (bf16*)p; p += W2 * 2;
    bf16* wq2 = (bf16*)p; p += W2 * 2;
    bf16* wk2 = (bf16*)p; p += W2 * 2;
    bf16* wv2 = (bf16*)p; p += W2 * 2;
    bf16* wo2 = (bf16*)p; p += W2 * 2;
    bf16* wff1 = (bf16*)p; p += WF * 2;
    bf16* wff2 = (bf16*)p; p += WF * 2;
    bf16* wctx = (bf16*)p; p += (size_t)TOKF * 2;
    bf16* X    = (bf16*)p; p += (size_t)TOKF * 2;
    bf16* Att  = (bf16*)p; p += (size_t)TOKF * 2;
    bf16* K2   = (bf16*)p; p += (size_t)TOKF * 2;
    bf16* V2   = (bf16*)p; p += (size_t)TOKF * 2;
    bf16* H    = (bf16*)p; p += (size_t)SEQN * DFF * 2;
    float* Qp  = (float*)p; p += (size_t)2 * TOKF * 4;   // split-K partial pairs
    float* Kp  = (float*)p; p += (size_t)2 * TOKF * 4;
    float* Vp  = (float*)p; p += (size_t)2 * TOKF * 4;
    float* X2p = (float*)p; p += (size_t)2 * TOKF * 4;

    const float* ctx7 = ctx_in + (size_t)7 * SEQN * D_EMB;

    // ---- weight conversions (wlin intentionally NOT converted) ----
    {
        CvtArgs a = {};
        a.src[0] = Wq1; a.dst[0] = wq1;  a.src[1] = Wk1; a.dst[1] = wk1;
        a.src[2] = Wv1; a.dst[2] = wv1;  a.src[3] = Wo1; a.dst[3] = wo1;
        a.src[4] = Wq2; a.dst[4] = wq2;  a.src[5] = Wk2; a.dst[5] = wk2;
        a.src[6] = Wv2; a.dst[6] = wv2;  a.src[7] = Wo2; a.dst[7] = wo2;
        int n4 = (int)(W2 / 4);
        hipLaunchKernelGGL(cvt_kernel, dim3((n4 + 255) / 256, 1, 8), dim3(256), 0,
                           stream, a, n4);
    }
    {
        CvtArgs a = {};
        a.src[0] = W_ff1; a.dst[0] = wff1;
        a.src[1] = W_ff2; a.dst[1] = wff2;
        int n4 = (int)(WF / 4);
        hipLaunchKernelGGL(cvt_kernel, dim3((n4 + 255) / 256, 1, 2), dim3(256), 0,
                           stream, a, n4);
    }
    {
        CvtArgs a = {};
        a.src[0] = ctx7; a.dst[0] = wctx;
        int n4 = TOKF / 4;
        hipLaunchKernelGGL(cvt_kernel, dim3((n4 + 255) / 256, 1, 1), dim3(256), 0,
                           stream, a, n4);
    }

    hipLaunchKernelGGL(add_pe_kernel, dim3((SEQN * D_EMB) / 256), dim3(256), 0,
                       stream, x_in, X);

    // cross-attn K2,V2 once (bf16 out, no split)
    launch_gemm(wctx, wk2, wv2, wv2, nullptr, nullptr, nullptr,
                K2, V2, V2, SEQN, D_EMB, D_EMB, 0, 1, 2, 1, stream);

    for (int layer = 0; layer < NLAYERS; ++layer) {
        // ---- self attention ----
        launch_gemm(X, wq1, wk1, wv1, nullptr, nullptr, nullptr,
                    Qp, Kp, Vp, SEQN, D_EMB, D_EMB, 0, 0, 3, 2, stream);
        hipLaunchKernelGGL(attn_token_kernel, dim3(SEQN), dim3(128), 0, stream,
                           Qp, Qp + TOKF, Kp, Kp + TOKF, Vp, Vp + TOKF,
                           (const bf16*)nullptr, (const bf16*)nullptr, Att, 1, 0);
        launch_gemm(Att, wo1, wo1, wo1, nullptr, nullptr, nullptr,
                    X2p, X2p, X2p, SEQN, D_EMB, D_EMB, 0, 0, 1, 2, stream);
        hipLaunchKernelGGL(layernorm_kernel, dim3(SEQN), dim3(256), 0, stream,
                           X2p, X2p + TOKF, (const float*)nullptr, g1, be1, X);

        // ---- cross attention ----
        launch_gemm(X, wq2, wq2, wq2, nullptr, nullptr, nullptr,
                    Qp, Qp, Qp, SEQN, D_EMB, D_EMB, 0, 0, 1, 2, stream);
        hipLaunchKernelGGL(attn_token_kernel, dim3(SEQN), dim3(128), 0, stream,
                           Qp, Qp + TOKF,
                           (const float*)nullptr, (const float*)nullptr,
                           (const float*)nullptr, (const float*)nullptr,
                           K2, V2, Att, 0, 1);
        launch_gemm(Att, wo2, wo2, wo2, nullptr, nullptr, nullptr,
                    X2p, X2p, X2p, SEQN, D_EMB, D_EMB, 0, 0, 1, 2, stream);
        hipLaunchKernelGGL(layernorm_kernel, dim3(SEQN), dim3(256), 0, stream,
                           X2p, X2p + TOKF, (const float*)nullptr, g2, be2, X);

        // ---- FFN ----
        launch_gemm(X, wff1, wff1, wff1, b_ff1, b_ff1, b_ff1,
                    H, H, H, SEQN, DFF, D_EMB, 1, 1, 1, 1, stream);
        launch_gemm(H, wff2, wff2, wff2, nullptr, nullptr, nullptr,
                    X2p, X2p, X2p, SEQN, D_EMB, DFF, 0, 0, 1, 2, stream);
        hipLaunchKernelGGL(layernorm_kernel, dim3(SEQN), dim3(256), 0, stream,
                           X2p, X2p + TOKF, b_ff2, g3, be3, X);
    }

    // fused logits GEMM + sequence-axis softmax (b_lin cancels)
    hipLaunchKernelGGL(logits_softmax_kernel, dim3((VOCAB + 63) / 64), dim3(256),
                       0, stream, X, W_lin, out);
}